// Round 15
// baseline (232.874 us; speedup 1.0000x reference)
//
#include <hip/hip_runtime.h>

#define N_NODES 50000
#define N_EDGES 800000
#define CAP 48
#define PB_BLOCKS 2560
typedef _Float16 f16;
typedef _Float16 h2 __attribute__((ext_vector_type(2)));
typedef _Float16 h4 __attribute__((ext_vector_type(4)));
// IN_F = 64, OUT_F = 64, EDGE_F = 16, d_in1 = 144
// NOTE: harness passes ALL integer inputs as int32 — edge_index is int32[2*E],
// src = ei[e], dst = ei[E+e].
// NOTE (round 3): hipLaunchCooperativeKernel broke the harness. NEVER coop.
// NOTE (round 6): few hot global atomic counters = serialization disaster.
// NOTE (round 9): __shfl honors EXEC — stage must be ALL-LANES-ACTIVE with
// clamped index. readlane ignores exec.
// NOTE (round 10): 32-wide single-chain stage = bank conflicts + VGPR
// serialization. 16-deep contiguous stage is the proven geometry.
// NOTE (rounds 11/13): FETCH 183->135->100MB with dur 83->76->74 ->
// nodefused is DEPENDENT-LATENCY-bound (no pipe saturated).
// NOTE (round 14): two-nodes-per-wave NEUTRAL (ILP gain == occupancy loss;
// LDS 2x, occ 62->42%). Wave-level TLP already covers in-wave ILP.
// Round 15: r13 structure + ONE change isolated from r14: slot row loaded
// unconditionally on j<CAP (stale tail lanes never dereferenced — all
// shfl/readlane indices clamped < dcap) -> cnt || slot in parallel,
// 3-hop chain becomes 2-hop.

#if defined(__has_builtin) && __has_builtin(__builtin_amdgcn_fdot2)
#define FDOT2(a, b, c) __builtin_amdgcn_fdot2((a), (b), (c), false)
#else
#define FDOT2(a, b, c) ((c) + (float)(a)[0] * (float)(b)[0] + (float)(a)[1] * (float)(b)[1])
#endif

// ---------------------------------------------------------------------------
// prebuild_kernel: EVERY block does
//   (1) build chunk: grid-stride over edges, bucket e by dst: slot=(src,e)
//   (2) pre chunk: xa = x @ W1[0:64,:] (fp16), xb = x @ W1[64:128,:] (fp32)
//       per-lane coalesced x load -> per-wave LDS row -> broadcast
//       ds_read_b128; next row software-pipelined; 4 accumulator chains.
// cnt/ocnt must be zeroed before launch (memsetAsync).
// ---------------------------------------------------------------------------
__global__ __launch_bounds__(256) void prebuild_kernel(
    const float* __restrict__ x, const float* __restrict__ W1,
    f16* __restrict__ xa, float* __restrict__ xb,
    const int* __restrict__ ei, unsigned* __restrict__ cnt,
    unsigned* __restrict__ ocnt, uint2* __restrict__ slot,
    unsigned* __restrict__ oflow)
{
    __shared__ __align__(16) float srow[4][64];   // per-wave x-row buffer

    const int tid = threadIdx.x;
    const int bid = blockIdx.x;

    // ---- build part: bucket edges by dst; slot holds (src, edge) 8 B ----
    for (int e = bid * 256 + tid; e < N_EDGES; e += PB_BLOCKS * 256) {
        const int s = ei[e];
        const int d = ei[N_EDGES + e];
        const unsigned pos = atomicAdd(&cnt[d], 1u);
        if (pos < CAP) {
            slot[(size_t)d * CAP + pos] = make_uint2((unsigned)s, (unsigned)e);
        } else {
            const unsigned oi = atomicAdd(ocnt, 1u);
            oflow[oi] = (unsigned)e;
        }
    }

    // ---- pre part: wave per (node-subset, product) ----
    const int w = tid >> 6;
    const int j = tid & 63;
    const int gw = bid * 4 + w;
    const int p = gw & 1;              // 0 -> xa (f16), 1 -> xb (f32)
    const int pair = gw >> 1;
    const int npair = PB_BLOCKS * 2;   // 5120

    float wc[64];
#pragma unroll
    for (int k = 0; k < 64; ++k) wc[k] = W1[(p * 64 + k) * 64 + j];

    if (pair < N_NODES) {
        float xv = x[(size_t)pair * 64 + j];          // pipelined row element
        for (int i = pair; i < N_NODES; i += npair) {
            srow[w][j] = xv;                           // wave-internal LDS write
            const int inext = i + npair;
            float xnext = 0.f;
            if (inext < N_NODES) xnext = x[(size_t)inext * 64 + j];

            float a0 = 0.f, a1 = 0.f, a2 = 0.f, a3 = 0.f;
#pragma unroll
            for (int k4 = 0; k4 < 4; ++k4) {
                const float4 v0 = *(const float4*)&srow[w][k4 * 16 + 0];
                const float4 v1 = *(const float4*)&srow[w][k4 * 16 + 4];
                const float4 v2 = *(const float4*)&srow[w][k4 * 16 + 8];
                const float4 v3 = *(const float4*)&srow[w][k4 * 16 + 12];
                a0 += v0.x * wc[k4 * 16 + 0];  a0 += v0.y * wc[k4 * 16 + 1];
                a0 += v0.z * wc[k4 * 16 + 2];  a0 += v0.w * wc[k4 * 16 + 3];
                a1 += v1.x * wc[k4 * 16 + 4];  a1 += v1.y * wc[k4 * 16 + 5];
                a1 += v1.z * wc[k4 * 16 + 6];  a1 += v1.w * wc[k4 * 16 + 7];
                a2 += v2.x * wc[k4 * 16 + 8];  a2 += v2.y * wc[k4 * 16 + 9];
                a2 += v2.z * wc[k4 * 16 + 10]; a2 += v2.w * wc[k4 * 16 + 11];
                a3 += v3.x * wc[k4 * 16 + 12]; a3 += v3.y * wc[k4 * 16 + 13];
                a3 += v3.z * wc[k4 * 16 + 14]; a3 += v3.w * wc[k4 * 16 + 15];
            }
            const float val = (a0 + a1) + (a2 + a3);
            if (p) xb[(size_t)i * 64 + j] = val;          // wave-uniform branch
            else   xa[(size_t)i * 64 + j] = (f16)val;
            xv = xnext;
        }
    }
}

// ---------------------------------------------------------------------------
// nodefused_kernel: one wave per dst node.
//   hacc = sum_e relu(xa[src]+xb[n]+ea@W1c+b1)    (aggregation)
//   out[n] = hacc @ W2 + deg*b2                   (W2 hoisted out of seg-sum)
// slot row loaded UNCONDITIONALLY (j<CAP) in parallel with cnt -> 2-hop
// dependent chain (slot->xa). 16-deep chunks; ea staged f16; dot2 consume;
// 2 hacc chains; overflow folded inline (deg>CAP, ~never). No out atomics.
// ---------------------------------------------------------------------------
__global__ __launch_bounds__(256) void nodefused_kernel(
    const f16* __restrict__ xa, const float* __restrict__ xb,
    const float* __restrict__ ea, const uint2* __restrict__ slot,
    const int* __restrict__ ei, const unsigned* __restrict__ cnt,
    const float* __restrict__ W1, const float* __restrict__ b1,
    const float* __restrict__ W2, const float* __restrict__ b2,
    const unsigned* __restrict__ ocnt, const unsigned* __restrict__ oflow,
    float* __restrict__ out)
{
    __shared__ __align__(16) f16   sea[4][CAP * 16];   // 6 KB: f16 ea tiles
    __shared__ __align__(16) float sh[4][64];          // 1 KB: hacc broadcast

    const int w = threadIdx.x >> 6;
    const int j = threadIdx.x & 63;
    const int n = blockIdx.x * 4 + w;

    // slot load issued UNCONDITIONALLY (j<CAP): stale tail entries are never
    // read — every shfl/readlane index is clamped < dcap. cnt flies parallel.
    uint2 my = make_uint2(0u, 0u);
    if (j < CAP) my = slot[(size_t)n * CAP + j];
    const int deg = (int)cnt[n];            // TRUE degree (may exceed CAP)
    const int dcap = deg < CAP ? deg : CAP;
    const int sv = (int)my.x;
    const int ev = (int)my.y;

    // W1c column j as 8 f16 pairs (for dot2)
    h2 w1h[8];
#pragma unroll
    for (int r = 0; r < 8; ++r) {
        w1h[r][0] = (f16)W1[(128 + 2 * r) * 64 + j];
        w1h[r][1] = (f16)W1[(128 + 2 * r + 1) * 64 + j];
    }
    const float b1j = b1[j];
    const float b2j = b2[j];

    const float base = xb[(size_t)n * 64 + j] + b1j;

    float hacc = 0.f;
    if (dcap > 0) {
        const int sub = j >> 2;        // which edge of the chunk this lane stages
        const int q   = j & 3;         // which 4-float quarter of that edge
        float h0 = 0.f, h1 = 0.f;      // split accumulator chains

        for (int b0 = 0; b0 < dcap; b0 += 16) {
            // ---- stage ea rows (f32 global -> f16 LDS), 1 b64 write/lane ----
            // ALL lanes active, clamped index (r9 lesson); contiguous bytes.
            {
                int ii = b0 + sub;
                const int ic = ii < dcap ? ii : dcap - 1;   // clamp: benign dup
                const unsigned eid = (unsigned)__shfl(ev, ic);
                float4 v = *(const float4*)(ea + (size_t)eid * 16 + q * 4);
                h4 pv = {(f16)v.x, (f16)v.y, (f16)v.z, (f16)v.w};
                *(h4*)&sea[w][ic * 16 + q * 4] = pv;
            }
            // ---- issue 16 xa gathers into registers (static indexing) ----
            float xv[16];
#pragma unroll
            for (int t = 0; t < 16; ++t) {
                int ii = b0 + t;
                const int ic = ii < dcap ? ii : dcap - 1;   // uniform select
                const unsigned ss =
                    (unsigned)__builtin_amdgcn_readlane(sv, ic);
                xv[t] = (float)xa[(size_t)ss * 64 + j];
            }
            // ---- consume 16 edges: 2 ds_read_b128 + 8 dot2 each ----
#pragma unroll
            for (int t = 0; t < 16; ++t) {
                const int ii = b0 + t;
                if (ii < dcap) {                            // uniform branch
                    uint4 r0 = *(const uint4*)&sea[w][ii * 16];
                    uint4 r1 = *(const uint4*)&sea[w][ii * 16 + 8];
                    float acc = base + xv[t];
                    acc = FDOT2(__builtin_bit_cast(h2, r0.x), w1h[0], acc);
                    acc = FDOT2(__builtin_bit_cast(h2, r0.y), w1h[1], acc);
                    acc = FDOT2(__builtin_bit_cast(h2, r0.z), w1h[2], acc);
                    acc = FDOT2(__builtin_bit_cast(h2, r0.w), w1h[3], acc);
                    acc = FDOT2(__builtin_bit_cast(h2, r1.x), w1h[4], acc);
                    acc = FDOT2(__builtin_bit_cast(h2, r1.y), w1h[5], acc);
                    acc = FDOT2(__builtin_bit_cast(h2, r1.z), w1h[6], acc);
                    acc = FDOT2(__builtin_bit_cast(h2, r1.w), w1h[7], acc);
                    if (t & 1) h1 += fmaxf(acc, 0.f);
                    else       h0 += fmaxf(acc, 0.f);
                }
            }
        }
        hacc = h0 + h1;
    }

    // ---- overflow fold (wave-uniform gate; expected never taken) ----
    if (deg > CAP) {
        const unsigned oc = *ocnt;
        for (unsigned t2 = 0; t2 < oc; ++t2) {
            const int e = (int)oflow[t2];
            if (ei[N_EDGES + e] == n) {
                const int s = ei[e];
                float acc = base + (float)xa[(size_t)s * 64 + j];
                for (int k = 0; k < 16; ++k)
                    acc += ea[(size_t)e * 16 + k] * W1[(128 + k) * 64 + j];
                hacc += fmaxf(acc, 0.f);
            }
        }
    }

    // ---- fused epilogue: out[n] = hacc @ W2 + deg * b2 ----
    sh[w][j] = hacc;                   // broadcast via LDS (wave-internal, f32)
    float msg = (float)deg * b2j;
#pragma unroll
    for (int k4 = 0; k4 < 16; ++k4) {
        float4 hv = *(const float4*)&sh[w][k4 * 4];         // uniform broadcast
        msg += hv.x * W2[(k4 * 4 + 0) * 64 + j];
        msg += hv.y * W2[(k4 * 4 + 1) * 64 + j];
        msg += hv.z * W2[(k4 * 4 + 2) * 64 + j];
        msg += hv.w * W2[(k4 * 4 + 3) * 64 + j];
    }
    out[(size_t)n * 64 + j] = msg;
}

// ---------------------------------------------------------------------------
// OLD PATH kernels (ws too small for bucketed pipeline) — fp32 throughout
// ---------------------------------------------------------------------------
__global__ __launch_bounds__(256) void pre_kernel(
    const float* __restrict__ x, const float* __restrict__ W1,
    float* __restrict__ xa, float* __restrict__ xb)
{
    const int w = threadIdx.x >> 6;
    const int j = threadIdx.x & 63;
    const int gw = blockIdx.x * 4 + w;
    const int p = gw & 1;
    const int pair = gw >> 1;
    const int npair = (gridDim.x * 4) >> 1;

    float wc[64];
#pragma unroll
    for (int k = 0; k < 64; ++k) wc[k] = W1[(p * 64 + k) * 64 + j];
    float* __restrict__ outp = p ? xb : xa;
    for (int i = pair; i < N_NODES; i += npair) {
        const float4* xr = (const float4*)&x[(size_t)i * 64];
        float acc = 0.f;
#pragma unroll
        for (int k4 = 0; k4 < 16; ++k4) {
            float4 xv = xr[k4];
            acc += xv.x * wc[k4 * 4 + 0];
            acc += xv.y * wc[k4 * 4 + 1];
            acc += xv.z * wc[k4 * 4 + 2];
            acc += xv.w * wc[k4 * 4 + 3];
        }
        outp[(size_t)i * 64 + j] = acc;
    }
}

__global__ __launch_bounds__(256) void edge_kernel(
    const float* __restrict__ xa, const float* __restrict__ xb,
    const int* __restrict__ ei,
    const float* __restrict__ edge_attr,
    const float* __restrict__ W1, const float* __restrict__ b1,
    const float* __restrict__ W2, const float* __restrict__ b2,
    float* __restrict__ out)
{
    __shared__ __align__(16) float eas[4][256];
    __shared__ __align__(16) float hs[4][16][64];

    const int w = threadIdx.x >> 6;
    const int j = threadIdx.x & 63;
    const int wt = blockIdx.x * 4 + w;
    const long eb = (long)wt * 16;

    float w1c[16];
    float w2c[64];
#pragma unroll
    for (int k = 0; k < 16; ++k) w1c[k] = W1[(128 + k) * 64 + j];
#pragma unroll
    for (int k = 0; k < 64; ++k) w2c[k] = W2[k * 64 + j];
    const float b1j = b1[j];
    const float b2j = b2[j];

    int idxv = 0;
    if (j < 16)       idxv = ei[eb + j];
    else if (j < 32)  idxv = ei[(long)N_EDGES + eb + (j - 16)];

    {
        float4 ev = *(const float4*)&edge_attr[eb * 16 + j * 4];
        *(float4*)&eas[w][j * 4] = ev;
    }

#pragma unroll 4
    for (int e = 0; e < 16; ++e) {
        const int s  = __shfl(idxv, e);
        const int dd = __shfl(idxv, 16 + e);

        float acc = xa[(long)s * 64 + j] + xb[(long)dd * 64 + j] + b1j;
#pragma unroll
        for (int k4 = 0; k4 < 4; ++k4) {
            float4 ev = *(const float4*)&eas[w][e * 16 + k4 * 4];
            acc += ev.x * w1c[k4 * 4 + 0];
            acc += ev.y * w1c[k4 * 4 + 1];
            acc += ev.z * w1c[k4 * 4 + 2];
            acc += ev.w * w1c[k4 * 4 + 3];
        }
        const float h = fmaxf(acc, 0.f);
        hs[w][e][j] = h;

        float msg = b2j;
#pragma unroll
        for (int k4 = 0; k4 < 16; ++k4) {
            float4 hv = *(const float4*)&hs[w][e][k4 * 4];
            msg += hv.x * w2c[k4 * 4 + 0];
            msg += hv.y * w2c[k4 * 4 + 1];
            msg += hv.z * w2c[k4 * 4 + 2];
            msg += hv.w * w2c[k4 * 4 + 3];
        }
        unsafeAtomicAdd(&out[(long)dd * 64 + j], msg);
    }
}

__global__ __launch_bounds__(256) void fallback_kernel(
    const float* __restrict__ x, const int* __restrict__ ei,
    const float* __restrict__ edge_attr,
    const float* __restrict__ W1, const float* __restrict__ b1,
    const float* __restrict__ W2, const float* __restrict__ b2,
    float* __restrict__ out)
{
    const int w = threadIdx.x >> 6;
    const int j = threadIdx.x & 63;
    const long e = (long)blockIdx.x * 4 + w;
    if (e >= N_EDGES) return;
    const int s  = ei[e];
    const int dd = ei[(long)N_EDGES + e];

    float acc = b1[j];
    for (int k = 0; k < 64; ++k) acc += x[(long)s  * 64 + k] * W1[k * 64 + j];
    for (int k = 0; k < 64; ++k) acc += x[(long)dd * 64 + k] * W1[(64 + k) * 64 + j];
    for (int k = 0; k < 16; ++k) acc += edge_attr[e * 16 + k] * W1[(128 + k) * 64 + j];
    const float h = fmaxf(acc, 0.f);

    float msg = b2[j];
    for (int k = 0; k < 64; ++k) msg += __shfl(h, k) * W2[k * 64 + j];
    unsafeAtomicAdd(&out[(long)dd * 64 + j], msg);
}

extern "C" void kernel_launch(void* const* d_in, const int* in_sizes, int n_in,
                              void* d_out, int out_size, void* d_ws, size_t ws_size,
                              hipStream_t stream) {
    const float* x   = (const float*)d_in[0];
    const int*   ei  = (const int*)d_in[1];
    const float* ea  = (const float*)d_in[2];
    const float* W1  = (const float*)d_in[3];
    const float* b1  = (const float*)d_in[4];
    const float* W2  = (const float*)d_in[5];
    const float* b2  = (const float*)d_in[6];
    float* out = (float*)d_out;

    const size_t NF = (size_t)N_NODES * 64;
    const size_t need_main = NF * 2 + NF * 4               // xa (f16), xb (f32)
                           + (size_t)N_NODES * 4 + 256     // cnt, ocnt(+pad)
                           + (size_t)N_NODES * CAP * 8     // slot (uint2)
                           + (size_t)N_EDGES * 4;          // oflow
    const size_t need_old = 2 * NF * 4;

    if (ws_size >= need_main) {
        char* p = (char*)d_ws;
        f16*      xauf  = (f16*)p;      p += NF * 2;
        float*    xbuf  = (float*)p;    p += NF * 4;
        unsigned* cnt   = (unsigned*)p; p += (size_t)N_NODES * 4;
        unsigned* ocnt  = (unsigned*)p; p += 256;
        uint2*    slot  = (uint2*)p;    p += (size_t)N_NODES * CAP * 8;
        unsigned* oflow = (unsigned*)p;

        hipMemsetAsync(cnt, 0, (size_t)N_NODES * 4 + 256, stream);
        prebuild_kernel<<<PB_BLOCKS, 256, 0, stream>>>(
            x, W1, xauf, xbuf, ei, cnt, ocnt, slot, oflow);
        nodefused_kernel<<<N_NODES / 4, 256, 0, stream>>>(
            xauf, xbuf, ea, slot, ei, cnt, W1, b1, W2, b2, ocnt, oflow, out);
    } else if (ws_size >= need_old) {
        hipMemsetAsync(out, 0, (size_t)N_NODES * 64 * sizeof(float), stream);
        float* xauf = (float*)d_ws;
        float* xbuf = xauf + NF;
        pre_kernel<<<512, 256, 0, stream>>>(x, W1, xauf, xbuf);
        edge_kernel<<<N_EDGES / 64, 256, 0, stream>>>(xauf, xbuf, ei, ea,
                                                      W1, b1, W2, b2, out);
    } else {
        hipMemsetAsync(out, 0, (size_t)N_NODES * 64 * sizeof(float), stream);
        fallback_kernel<<<N_EDGES / 4, 256, 0, stream>>>(x, ei, ea,
                                                         W1, b1, W2, b2, out);
    }
}

// Round 16
// 219.514 us; speedup vs baseline: 1.0609x; 1.0609x over previous
//
#include <hip/hip_runtime.h>

#define N_NODES 50000
#define N_EDGES 800000
#define CAP 48
#define PB_BLOCKS 2560
typedef _Float16 f16;
typedef _Float16 h2 __attribute__((ext_vector_type(2)));
typedef _Float16 h4 __attribute__((ext_vector_type(4)));
// IN_F = 64, OUT_F = 64, EDGE_F = 16, d_in1 = 144
// NOTE: harness passes ALL integer inputs as int32 — edge_index is int32[2*E],
// src = ei[e], dst = ei[E+e].
// NOTE (round 3): hipLaunchCooperativeKernel broke the harness. NEVER coop.
// NOTE (round 6): few hot global atomic counters = serialization disaster.
// NOTE (round 9): __shfl honors EXEC — stage must be ALL-LANES-ACTIVE with
// clamped index. readlane ignores exec.
// NOTE (round 10): depth-32 stage = bank conflicts + VGPR spill-serialized
// gathers. 16-deep contiguous stage is the proven geometry.
// NOTE (round 11): FETCH 183->135MB changed duration 0% -> not BW-bound.
// NOTE (round 12): dot2 cut VALUBusy 70->51%, dur 83->76.
// NOTE (round 13): uint2 slot removed the ei hop: FETCH 135->100MB, 76->74.
// NOTE (round 14): two-nodes-per-wave NEUTRAL (ILP gain == occupancy loss).
// NOTE (round 15): unconditional slot load REGRESSED (74->86us): VGPR 36->48,
// occ 62->45% — holding CAP-wide rows live beats TLP. dcap-bounded is right.
// Round 16: REVERT to round-13 verbatim (best measured: 223.1us total,
// nodefused 74us). nodefused is at its scattered-gather latency floor for
// this decomposition; wave TLP provides the overlap.

#if defined(__has_builtin) && __has_builtin(__builtin_amdgcn_fdot2)
#define FDOT2(a, b, c) __builtin_amdgcn_fdot2((a), (b), (c), false)
#else
#define FDOT2(a, b, c) ((c) + (float)(a)[0] * (float)(b)[0] + (float)(a)[1] * (float)(b)[1])
#endif

// ---------------------------------------------------------------------------
// prebuild_kernel: EVERY block does
//   (1) build chunk: grid-stride over edges, bucket e by dst: slot=(src,e)
//   (2) pre chunk: xa = x @ W1[0:64,:] (fp16), xb = x @ W1[64:128,:] (fp32)
//       per-lane coalesced x load -> per-wave LDS row -> broadcast
//       ds_read_b128; next row software-pipelined; 4 accumulator chains.
// cnt/ocnt must be zeroed before launch (memsetAsync).
// ---------------------------------------------------------------------------
__global__ __launch_bounds__(256) void prebuild_kernel(
    const float* __restrict__ x, const float* __restrict__ W1,
    f16* __restrict__ xa, float* __restrict__ xb,
    const int* __restrict__ ei, unsigned* __restrict__ cnt,
    unsigned* __restrict__ ocnt, uint2* __restrict__ slot,
    unsigned* __restrict__ oflow)
{
    __shared__ __align__(16) float srow[4][64];   // per-wave x-row buffer

    const int tid = threadIdx.x;
    const int bid = blockIdx.x;

    // ---- build part: bucket edges by dst; slot holds (src, edge) 8 B ----
    for (int e = bid * 256 + tid; e < N_EDGES; e += PB_BLOCKS * 256) {
        const int s = ei[e];
        const int d = ei[N_EDGES + e];
        const unsigned pos = atomicAdd(&cnt[d], 1u);
        if (pos < CAP) {
            slot[(size_t)d * CAP + pos] = make_uint2((unsigned)s, (unsigned)e);
        } else {
            const unsigned oi = atomicAdd(ocnt, 1u);
            oflow[oi] = (unsigned)e;
        }
    }

    // ---- pre part: wave per (node-subset, product) ----
    const int w = tid >> 6;
    const int j = tid & 63;
    const int gw = bid * 4 + w;
    const int p = gw & 1;              // 0 -> xa (f16), 1 -> xb (f32)
    const int pair = gw >> 1;
    const int npair = PB_BLOCKS * 2;   // 5120

    float wc[64];
#pragma unroll
    for (int k = 0; k < 64; ++k) wc[k] = W1[(p * 64 + k) * 64 + j];

    if (pair < N_NODES) {
        float xv = x[(size_t)pair * 64 + j];          // pipelined row element
        for (int i = pair; i < N_NODES; i += npair) {
            srow[w][j] = xv;                           // wave-internal LDS write
            const int inext = i + npair;
            float xnext = 0.f;
            if (inext < N_NODES) xnext = x[(size_t)inext * 64 + j];

            float a0 = 0.f, a1 = 0.f, a2 = 0.f, a3 = 0.f;
#pragma unroll
            for (int k4 = 0; k4 < 4; ++k4) {
                const float4 v0 = *(const float4*)&srow[w][k4 * 16 + 0];
                const float4 v1 = *(const float4*)&srow[w][k4 * 16 + 4];
                const float4 v2 = *(const float4*)&srow[w][k4 * 16 + 8];
                const float4 v3 = *(const float4*)&srow[w][k4 * 16 + 12];
                a0 += v0.x * wc[k4 * 16 + 0];  a0 += v0.y * wc[k4 * 16 + 1];
                a0 += v0.z * wc[k4 * 16 + 2];  a0 += v0.w * wc[k4 * 16 + 3];
                a1 += v1.x * wc[k4 * 16 + 4];  a1 += v1.y * wc[k4 * 16 + 5];
                a1 += v1.z * wc[k4 * 16 + 6];  a1 += v1.w * wc[k4 * 16 + 7];
                a2 += v2.x * wc[k4 * 16 + 8];  a2 += v2.y * wc[k4 * 16 + 9];
                a2 += v2.z * wc[k4 * 16 + 10]; a2 += v2.w * wc[k4 * 16 + 11];
                a3 += v3.x * wc[k4 * 16 + 12]; a3 += v3.y * wc[k4 * 16 + 13];
                a3 += v3.z * wc[k4 * 16 + 14]; a3 += v3.w * wc[k4 * 16 + 15];
            }
            const float val = (a0 + a1) + (a2 + a3);
            if (p) xb[(size_t)i * 64 + j] = val;          // wave-uniform branch
            else   xa[(size_t)i * 64 + j] = (f16)val;
            xv = xnext;
        }
    }
}

// ---------------------------------------------------------------------------
// nodefused_kernel: one wave per dst node.
//   hacc = sum_e relu(xa[src]+xb[n]+ea@W1c+b1)    (aggregation)
//   out[n] = hacc @ W2 + deg*b2                   (W2 hoisted out of seg-sum)
// uint2 slot gives (src,e) in ONE scattered load -> 2-hop chain (slot->xa).
// 16-deep chunks; ea staged f16; dot2 consume; 2 hacc chains; overflow
// folded inline (deg>CAP, ~never). No atomics on out.
// ---------------------------------------------------------------------------
__global__ __launch_bounds__(256) void nodefused_kernel(
    const f16* __restrict__ xa, const float* __restrict__ xb,
    const float* __restrict__ ea, const uint2* __restrict__ slot,
    const int* __restrict__ ei, const unsigned* __restrict__ cnt,
    const float* __restrict__ W1, const float* __restrict__ b1,
    const float* __restrict__ W2, const float* __restrict__ b2,
    const unsigned* __restrict__ ocnt, const unsigned* __restrict__ oflow,
    float* __restrict__ out)
{
    __shared__ __align__(16) f16   sea[4][CAP * 16];   // 6 KB: f16 ea tiles
    __shared__ __align__(16) float sh[4][64];          // 1 KB: hacc broadcast

    const int w = threadIdx.x >> 6;
    const int j = threadIdx.x & 63;
    const int n = blockIdx.x * 4 + w;

    // W1c column j as 8 f16 pairs (for dot2)
    h2 w1h[8];
#pragma unroll
    for (int r = 0; r < 8; ++r) {
        w1h[r][0] = (f16)W1[(128 + 2 * r) * 64 + j];
        w1h[r][1] = (f16)W1[(128 + 2 * r + 1) * 64 + j];
    }
    const float b1j = b1[j];
    const float b2j = b2[j];

    const int deg = (int)cnt[n];            // TRUE degree (may exceed CAP)
    const int dcap = deg < CAP ? deg : CAP;

    // ONE scattered load gives both src and edge id (no ei hop)
    uint2 my = make_uint2(0u, 0u);
    if (j < dcap) my = slot[(size_t)n * CAP + j];
    const int sv = (int)my.x;
    const int ev = (int)my.y;

    const float base = xb[(size_t)n * 64 + j] + b1j;

    float hacc = 0.f;
    if (dcap > 0) {
        const int sub = j >> 2;        // which edge of the chunk this lane stages
        const int q   = j & 3;         // which 4-float quarter of that edge
        float h0 = 0.f, h1 = 0.f;      // split accumulator chains

        for (int b0 = 0; b0 < dcap; b0 += 16) {
            // ---- stage ea rows (f32 global -> f16 LDS), 1 b64 write/lane ----
            // ALL lanes active, clamped index (r9 lesson); contiguous bytes.
            {
                int ii = b0 + sub;
                const int ic = ii < dcap ? ii : dcap - 1;   // clamp: benign dup
                const unsigned eid = (unsigned)__shfl(ev, ic);
                float4 v = *(const float4*)(ea + (size_t)eid * 16 + q * 4);
                h4 pv = {(f16)v.x, (f16)v.y, (f16)v.z, (f16)v.w};
                *(h4*)&sea[w][ic * 16 + q * 4] = pv;
            }
            // ---- issue 16 xa gathers into registers (static indexing) ----
            float xv[16];
#pragma unroll
            for (int t = 0; t < 16; ++t) {
                int ii = b0 + t;
                const int ic = ii < dcap ? ii : dcap - 1;   // uniform select
                const unsigned ss =
                    (unsigned)__builtin_amdgcn_readlane(sv, ic);
                xv[t] = (float)xa[(size_t)ss * 64 + j];
            }
            // ---- consume 16 edges: 2 ds_read_b128 + 8 dot2 each ----
#pragma unroll
            for (int t = 0; t < 16; ++t) {
                const int ii = b0 + t;
                if (ii < dcap) {                            // uniform branch
                    uint4 r0 = *(const uint4*)&sea[w][ii * 16];
                    uint4 r1 = *(const uint4*)&sea[w][ii * 16 + 8];
                    float acc = base + xv[t];
                    acc = FDOT2(__builtin_bit_cast(h2, r0.x), w1h[0], acc);
                    acc = FDOT2(__builtin_bit_cast(h2, r0.y), w1h[1], acc);
                    acc = FDOT2(__builtin_bit_cast(h2, r0.z), w1h[2], acc);
                    acc = FDOT2(__builtin_bit_cast(h2, r0.w), w1h[3], acc);
                    acc = FDOT2(__builtin_bit_cast(h2, r1.x), w1h[4], acc);
                    acc = FDOT2(__builtin_bit_cast(h2, r1.y), w1h[5], acc);
                    acc = FDOT2(__builtin_bit_cast(h2, r1.z), w1h[6], acc);
                    acc = FDOT2(__builtin_bit_cast(h2, r1.w), w1h[7], acc);
                    if (t & 1) h1 += fmaxf(acc, 0.f);
                    else       h0 += fmaxf(acc, 0.f);
                }
            }
        }
        hacc = h0 + h1;
    }

    // ---- overflow fold (wave-uniform gate; expected never taken) ----
    if (deg > CAP) {
        const unsigned oc = *ocnt;
        for (unsigned t2 = 0; t2 < oc; ++t2) {
            const int e = (int)oflow[t2];
            if (ei[N_EDGES + e] == n) {
                const int s = ei[e];
                float acc = base + (float)xa[(size_t)s * 64 + j];
                for (int k = 0; k < 16; ++k)
                    acc += ea[(size_t)e * 16 + k] * W1[(128 + k) * 64 + j];
                hacc += fmaxf(acc, 0.f);
            }
        }
    }

    // ---- fused epilogue: out[n] = hacc @ W2 + deg * b2 ----
    sh[w][j] = hacc;                   // broadcast via LDS (wave-internal, f32)
    float msg = (float)deg * b2j;
#pragma unroll
    for (int k4 = 0; k4 < 16; ++k4) {
        float4 hv = *(const float4*)&sh[w][k4 * 4];         // uniform broadcast
        msg += hv.x * W2[(k4 * 4 + 0) * 64 + j];
        msg += hv.y * W2[(k4 * 4 + 1) * 64 + j];
        msg += hv.z * W2[(k4 * 4 + 2) * 64 + j];
        msg += hv.w * W2[(k4 * 4 + 3) * 64 + j];
    }
    out[(size_t)n * 64 + j] = msg;
}

// ---------------------------------------------------------------------------
// OLD PATH kernels (ws too small for bucketed pipeline) — fp32 throughout
// ---------------------------------------------------------------------------
__global__ __launch_bounds__(256) void pre_kernel(
    const float* __restrict__ x, const float* __restrict__ W1,
    float* __restrict__ xa, float* __restrict__ xb)
{
    const int w = threadIdx.x >> 6;
    const int j = threadIdx.x & 63;
    const int gw = blockIdx.x * 4 + w;
    const int p = gw & 1;
    const int pair = gw >> 1;
    const int npair = (gridDim.x * 4) >> 1;

    float wc[64];
#pragma unroll
    for (int k = 0; k < 64; ++k) wc[k] = W1[(p * 64 + k) * 64 + j];
    float* __restrict__ outp = p ? xb : xa;
    for (int i = pair; i < N_NODES; i += npair) {
        const float4* xr = (const float4*)&x[(size_t)i * 64];
        float acc = 0.f;
#pragma unroll
        for (int k4 = 0; k4 < 16; ++k4) {
            float4 xv = xr[k4];
            acc += xv.x * wc[k4 * 4 + 0];
            acc += xv.y * wc[k4 * 4 + 1];
            acc += xv.z * wc[k4 * 4 + 2];
            acc += xv.w * wc[k4 * 4 + 3];
        }
        outp[(size_t)i * 64 + j] = acc;
    }
}

__global__ __launch_bounds__(256) void edge_kernel(
    const float* __restrict__ xa, const float* __restrict__ xb,
    const int* __restrict__ ei,
    const float* __restrict__ edge_attr,
    const float* __restrict__ W1, const float* __restrict__ b1,
    const float* __restrict__ W2, const float* __restrict__ b2,
    float* __restrict__ out)
{
    __shared__ __align__(16) float eas[4][256];
    __shared__ __align__(16) float hs[4][16][64];

    const int w = threadIdx.x >> 6;
    const int j = threadIdx.x & 63;
    const int wt = blockIdx.x * 4 + w;
    const long eb = (long)wt * 16;

    float w1c[16];
    float w2c[64];
#pragma unroll
    for (int k = 0; k < 16; ++k) w1c[k] = W1[(128 + k) * 64 + j];
#pragma unroll
    for (int k = 0; k < 64; ++k) w2c[k] = W2[k * 64 + j];
    const float b1j = b1[j];
    const float b2j = b2[j];

    int idxv = 0;
    if (j < 16)       idxv = ei[eb + j];
    else if (j < 32)  idxv = ei[(long)N_EDGES + eb + (j - 16)];

    {
        float4 ev = *(const float4*)&edge_attr[eb * 16 + j * 4];
        *(float4*)&eas[w][j * 4] = ev;
    }

#pragma unroll 4
    for (int e = 0; e < 16; ++e) {
        const int s  = __shfl(idxv, e);
        const int dd = __shfl(idxv, 16 + e);

        float acc = xa[(long)s * 64 + j] + xb[(long)dd * 64 + j] + b1j;
#pragma unroll
        for (int k4 = 0; k4 < 4; ++k4) {
            float4 ev = *(const float4*)&eas[w][e * 16 + k4 * 4];
            acc += ev.x * w1c[k4 * 4 + 0];
            acc += ev.y * w1c[k4 * 4 + 1];
            acc += ev.z * w1c[k4 * 4 + 2];
            acc += ev.w * w1c[k4 * 4 + 3];
        }
        const float h = fmaxf(acc, 0.f);
        hs[w][e][j] = h;

        float msg = b2j;
#pragma unroll
        for (int k4 = 0; k4 < 16; ++k4) {
            float4 hv = *(const float4*)&hs[w][e][k4 * 4];
            msg += hv.x * w2c[k4 * 4 + 0];
            msg += hv.y * w2c[k4 * 4 + 1];
            msg += hv.z * w2c[k4 * 4 + 2];
            msg += hv.w * w2c[k4 * 4 + 3];
        }
        unsafeAtomicAdd(&out[(long)dd * 64 + j], msg);
    }
}

__global__ __launch_bounds__(256) void fallback_kernel(
    const float* __restrict__ x, const int* __restrict__ ei,
    const float* __restrict__ edge_attr,
    const float* __restrict__ W1, const float* __restrict__ b1,
    const float* __restrict__ W2, const float* __restrict__ b2,
    float* __restrict__ out)
{
    const int w = threadIdx.x >> 6;
    const int j = threadIdx.x & 63;
    const long e = (long)blockIdx.x * 4 + w;
    if (e >= N_EDGES) return;
    const int s  = ei[e];
    const int dd = ei[(long)N_EDGES + e];

    float acc = b1[j];
    for (int k = 0; k < 64; ++k) acc += x[(long)s  * 64 + k] * W1[k * 64 + j];
    for (int k = 0; k < 64; ++k) acc += x[(long)dd * 64 + k] * W1[(64 + k) * 64 + j];
    for (int k = 0; k < 16; ++k) acc += edge_attr[e * 16 + k] * W1[(128 + k) * 64 + j];
    const float h = fmaxf(acc, 0.f);

    float msg = b2[j];
    for (int k = 0; k < 64; ++k) msg += __shfl(h, k) * W2[k * 64 + j];
    unsafeAtomicAdd(&out[(long)dd * 64 + j], msg);
}

extern "C" void kernel_launch(void* const* d_in, const int* in_sizes, int n_in,
                              void* d_out, int out_size, void* d_ws, size_t ws_size,
                              hipStream_t stream) {
    const float* x   = (const float*)d_in[0];
    const int*   ei  = (const int*)d_in[1];
    const float* ea  = (const float*)d_in[2];
    const float* W1  = (const float*)d_in[3];
    const float* b1  = (const float*)d_in[4];
    const float* W2  = (const float*)d_in[5];
    const float* b2  = (const float*)d_in[6];
    float* out = (float*)d_out;

    const size_t NF = (size_t)N_NODES * 64;
    const size_t need_main = NF * 2 + NF * 4               // xa (f16), xb (f32)
                           + (size_t)N_NODES * 4 + 256     // cnt, ocnt(+pad)
                           + (size_t)N_NODES * CAP * 8     // slot (uint2)
                           + (size_t)N_EDGES * 4;          // oflow
    const size_t need_old = 2 * NF * 4;

    if (ws_size >= need_main) {
        char* p = (char*)d_ws;
        f16*      xauf  = (f16*)p;      p += NF * 2;
        float*    xbuf  = (float*)p;    p += NF * 4;
        unsigned* cnt   = (unsigned*)p; p += (size_t)N_NODES * 4;
        unsigned* ocnt  = (unsigned*)p; p += 256;
        uint2*    slot  = (uint2*)p;    p += (size_t)N_NODES * CAP * 8;
        unsigned* oflow = (unsigned*)p;

        hipMemsetAsync(cnt, 0, (size_t)N_NODES * 4 + 256, stream);
        prebuild_kernel<<<PB_BLOCKS, 256, 0, stream>>>(
            x, W1, xauf, xbuf, ei, cnt, ocnt, slot, oflow);
        nodefused_kernel<<<N_NODES / 4, 256, 0, stream>>>(
            xauf, xbuf, ea, slot, ei, cnt, W1, b1, W2, b2, ocnt, oflow, out);
    } else if (ws_size >= need_old) {
        hipMemsetAsync(out, 0, (size_t)N_NODES * 64 * sizeof(float), stream);
        float* xauf = (float*)d_ws;
        float* xbuf = xauf + NF;
        pre_kernel<<<512, 256, 0, stream>>>(x, W1, xauf, xbuf);
        edge_kernel<<<N_EDGES / 64, 256, 0, stream>>>(xauf, xbuf, ei, ea,
                                                      W1, b1, W2, b2, out);
    } else {
        hipMemsetAsync(out, 0, (size_t)N_NODES * 64 * sizeof(float), stream);
        fallback_kernel<<<N_EDGES / 4, 256, 0, stream>>>(x, ei, ea,
                                                         W1, b1, W2, b2, out);
    }
}